// Round 3
// baseline (495.071 us; speedup 1.0000x reference)
//
#include <hip/hip_runtime.h>

// Problem constants (fixed by reference)
#define BB 16
#define SS 1024
#define NIN 7
#define NHID 28
#define NH 7
#define DH 4

constexpr int ROWS = BB * SS;                 // 16384
constexpr int QKV_ELEMS = BB * NH * SS * DH;  // 458752 floats per tensor

// ---------------------------------------------------------------------------
// Kernel 1: QKV projection. inputs [B,S,7] @ W[7,28] + b -> Q,K,V in
// head-major layout [B][H][S][4]. Q pre-scaled by 1/sqrt(DH)=0.5.
// ---------------------------------------------------------------------------
__global__ __launch_bounds__(256) void k_proj(
    const float* __restrict__ inp,
    const float* __restrict__ Wq, const float* __restrict__ bq,
    const float* __restrict__ Wk, const float* __restrict__ bk,
    const float* __restrict__ Wv, const float* __restrict__ bv,
    float* __restrict__ Qo, float* __restrict__ Ko, float* __restrict__ Vo)
{
    __shared__ float  xs[256 * NIN];   // 7 KB: 256 rows of inputs
    __shared__ float4 w4[147];         // Wq(49) | Wk(49) | Wv(49) as float4
    __shared__ float4 b4[21];          // bq(7) | bk(7) | bv(7)

    const int tid  = threadIdx.x;
    const int row0 = blockIdx.x * 256;

    #pragma unroll
    for (int i = 0; i < NIN; ++i) xs[tid + 256 * i] = inp[row0 * NIN + tid + 256 * i];

    if (tid < 147) {
        const float* src = (tid < 49) ? Wq : (tid < 98) ? Wk : Wv;
        int off = (tid < 49) ? tid : (tid < 98) ? tid - 49 : tid - 98;
        w4[tid] = ((const float4*)src)[off];
    } else if (tid < 168) {
        int t = tid - 147;
        const float* src = (t < 7) ? bq : (t < 14) ? bk : bv;
        b4[t] = ((const float4*)src)[t % 7];
    }
    __syncthreads();

    const int r = row0 + tid;
    const int b = r >> 10, s = r & 1023;

    float x[NIN];
    #pragma unroll
    for (int i = 0; i < NIN; ++i) x[i] = xs[tid * NIN + i];

    float4 q[NH], k[NH], v[NH];
    #pragma unroll
    for (int j4 = 0; j4 < NH; ++j4) { q[j4] = b4[j4]; k[j4] = b4[7 + j4]; v[j4] = b4[14 + j4]; }

    #pragma unroll
    for (int i = 0; i < NIN; ++i) {
        const float xi = x[i];
        #pragma unroll
        for (int j4 = 0; j4 < NH; ++j4) {
            float4 wq = w4[i * 7 + j4];
            float4 wk = w4[49 + i * 7 + j4];
            float4 wv = w4[98 + i * 7 + j4];
            q[j4].x += xi * wq.x; q[j4].y += xi * wq.y; q[j4].z += xi * wq.z; q[j4].w += xi * wq.w;
            k[j4].x += xi * wk.x; k[j4].y += xi * wk.y; k[j4].z += xi * wk.z; k[j4].w += xi * wk.w;
            v[j4].x += xi * wv.x; v[j4].y += xi * wv.y; v[j4].z += xi * wv.z; v[j4].w += xi * wv.w;
        }
    }

    #pragma unroll
    for (int j4 = 0; j4 < NH; ++j4) {
        const int idx = (b * NH + j4) * SS + s;   // float4 index
        float4 qs = make_float4(0.5f * q[j4].x, 0.5f * q[j4].y, 0.5f * q[j4].z, 0.5f * q[j4].w);
        ((float4*)Qo)[idx] = qs;
        ((float4*)Ko)[idx] = k[j4];
        ((float4*)Vo)[idx] = v[j4];
    }
}

// ---------------------------------------------------------------------------
// Kernel 2: attention 1, 2-way k-split. Block = (b,h,qtile 128), 256 threads:
// thread (ql = tid&127, kh = tid>>7) covers keys [kh*512, kh*512+512).
// Halved dependence chain + 2 independent accumulator pairs inside;
// merge the two k-halves through LDS with one barrier.
// ---------------------------------------------------------------------------
__global__ __launch_bounds__(256) void k_attn1(
    const float* __restrict__ Qo, const float* __restrict__ Ko,
    const float* __restrict__ Vo, float* __restrict__ A)
{
    __shared__ float4 Ksh[SS];    // 16 KB
    __shared__ float4 Vsh[SS];    // 16 KB
    __shared__ float4 pacc[128];  // partial acc from kh=1
    __shared__ float  pl[128];

    const int bh  = blockIdx.x >> 3;
    const int qt  = blockIdx.x & 7;
    const int tid = threadIdx.x;

    const float4* Kg = (const float4*)Ko + (size_t)bh * SS;
    const float4* Vg = (const float4*)Vo + (size_t)bh * SS;
    #pragma unroll
    for (int i = 0; i < 4; ++i) {
        Ksh[tid + 256 * i] = Kg[tid + 256 * i];
        Vsh[tid + 256 * i] = Vg[tid + 256 * i];
    }
    __syncthreads();

    const int ql = tid & 127;
    const int kh = tid >> 7;
    const int q  = qt * 128 + ql;
    const float4 qv = ((const float4*)Qo)[(size_t)bh * SS + q];

    float4 acc0 = make_float4(0.f, 0.f, 0.f, 0.f);
    float4 acc1 = make_float4(0.f, 0.f, 0.f, 0.f);
    float l0 = 0.f, l1 = 0.f;
    const int k0 = kh << 9;

    #pragma unroll 4
    for (int kk = k0; kk < k0 + 512; kk += 2) {
        float4 ka = Ksh[kk];
        float4 kb = Ksh[kk + 1];
        float sa = qv.x * ka.x + qv.y * ka.y + qv.z * ka.z + qv.w * ka.w;
        float sb = qv.x * kb.x + qv.y * kb.y + qv.z * kb.z + qv.w * kb.w;
        float pa = __expf(sa);
        float pb = __expf(sb);
        float4 va = Vsh[kk];
        float4 vb = Vsh[kk + 1];
        l0 += pa; l1 += pb;
        acc0.x += pa * va.x; acc0.y += pa * va.y; acc0.z += pa * va.z; acc0.w += pa * va.w;
        acc1.x += pb * vb.x; acc1.y += pb * vb.y; acc1.z += pb * vb.z; acc1.w += pb * vb.w;
    }
    float  l   = l0 + l1;
    float4 acc = make_float4(acc0.x + acc1.x, acc0.y + acc1.y,
                             acc0.z + acc1.z, acc0.w + acc1.w);

    if (kh) { pacc[ql] = acc; pl[ql] = l; }
    __syncthreads();
    if (!kh) {
        float4 pa = pacc[ql];
        acc.x += pa.x; acc.y += pa.y; acc.z += pa.z; acc.w += pa.w;
        l += pl[ql];
        const float inv = 1.f / l;
        const int b = bh / NH, h = bh % NH;
        ((float4*)A)[(size_t)(b * SS + q) * NH + h] =
            make_float4(acc.x * inv, acc.y * inv, acc.z * inv, acc.w * inv);
    }
}

// ---------------------------------------------------------------------------
// Kernel 3: LayerNorm(28) + FFN(28->7)+ReLU+residual -> out (output 0),
// then Q2 (row-major, pre-scaled 1/sqrt(7)) and K2 TRANSPOSED: K2T[b][d][s].
// ---------------------------------------------------------------------------
__global__ __launch_bounds__(256) void k_lnffn(
    const float* __restrict__ A, const float* __restrict__ inp,
    const float* __restrict__ lnw, const float* __restrict__ lnb,
    const float* __restrict__ W1, const float* __restrict__ b1,
    const float* __restrict__ Wq2, const float* __restrict__ bq2,
    const float* __restrict__ Wk2, const float* __restrict__ bk2,
    float* __restrict__ outp, float* __restrict__ Q2, float* __restrict__ K2T)
{
    const int r = blockIdx.x * 256 + threadIdx.x;

    float y[NHID];
    const float4* Ar = (const float4*)A + (size_t)r * 7;
    float mu = 0.f;
    #pragma unroll
    for (int j4 = 0; j4 < 7; ++j4) {
        float4 t = Ar[j4];
        y[4 * j4 + 0] = t.x; y[4 * j4 + 1] = t.y; y[4 * j4 + 2] = t.z; y[4 * j4 + 3] = t.w;
        mu += t.x + t.y + t.z + t.w;
    }
    mu *= (1.f / NHID);
    float var = 0.f;
    #pragma unroll
    for (int j = 0; j < NHID; ++j) { float d = y[j] - mu; var += d * d; }
    var *= (1.f / NHID);
    const float rstd = rsqrtf(var + 1e-5f);
    #pragma unroll
    for (int j = 0; j < NHID; ++j) y[j] = (y[j] - mu) * rstd * lnw[j] + lnb[j];

    float o[NIN];
    #pragma unroll
    for (int i = 0; i < NIN; ++i) {
        float a = b1[i];
        #pragma unroll
        for (int j = 0; j < NHID; ++j) a += y[j] * W1[j * NIN + i];
        o[i] = fmaxf(a, 0.f) + inp[r * NIN + i];
        outp[r * NIN + i] = o[i];
    }

    const float rs7 = 0.3779644730092272f;  // 1/sqrt(7)
    const int b = r >> 10, s = r & 1023;
    float* K2Tb = K2T + ((size_t)b * NHID) * SS + s;
    float4* Q2r = (float4*)Q2 + (size_t)r * 7;
    #pragma unroll
    for (int j4 = 0; j4 < 7; ++j4) {
        float qq[4];
        #pragma unroll
        for (int c = 0; c < 4; ++c) {
            int j = 4 * j4 + c;
            float aq = bq2[j], ak = bk2[j];
            #pragma unroll
            for (int i = 0; i < NIN; ++i) {
                aq += o[i] * Wq2[i * NHID + j];
                ak += o[i] * Wk2[i * NHID + j];
            }
            qq[c] = aq * rs7;
            K2Tb[(size_t)j * SS] = ak;      // coalesced per-j
        }
        Q2r[j4] = make_float4(qq[0], qq[1], qq[2], qq[3]);
    }
}

// ---------------------------------------------------------------------------
// Kernel 4: attention 2 weights. WAVE-AUTONOMOUS: each wave owns 4 complete
// query rows (block = 4 waves = 16 rows; grid = 1024 blocks). Lane holds
// key-f4-chunks {lane+64j, j=0..3} for each row: p[4][4] float4 = 64 VGPRs.
// Row sum = 64-lane shfl_xor butterfly -> no LDS atomics, no store-gating
// barrier; each wave stores its rows as soon as ITS compute is done.
// K2T loads lane-contiguous; q via LDS broadcast (one staging barrier only).
// ---------------------------------------------------------------------------
#define QR 4
__global__ __launch_bounds__(256, 4) void k_attn2(
    const float* __restrict__ Q2, const float* __restrict__ K2T,
    float* __restrict__ out2)
{
    __shared__ float q2s[16 * NHID];   // 448 floats

    const int tid  = threadIdx.x;
    const int lane = tid & 63;
    const int wid  = tid >> 6;
    const int row0 = blockIdx.x * 16;          // global row = b*1024 + s
    const int b    = row0 >> 10;

    if (tid < 112) ((float4*)q2s)[tid] = ((const float4*)Q2)[(size_t)row0 * 7 + tid];
    __syncthreads();

    const float*  qw  = q2s + wid * QR * NHID;              // this wave's 4 rows
    const float4* K2b = (const float4*)(K2T + (size_t)b * NHID * SS);  // [28][256] f4

    float4 p[QR][4];
    #pragma unroll
    for (int r = 0; r < QR; ++r)
        #pragma unroll
        for (int j = 0; j < 4; ++j) p[r][j] = make_float4(0.f, 0.f, 0.f, 0.f);

    #pragma unroll
    for (int d4 = 0; d4 < 7; ++d4) {
        float4 qv[QR];
        #pragma unroll
        for (int r = 0; r < QR; ++r) qv[r] = ((const float4*)qw)[r * 7 + d4];  // broadcast
        #pragma unroll
        for (int dd = 0; dd < 4; ++dd) {
            const int d = d4 * 4 + dd;
            float4 kt0 = K2b[d * 256 +       lane];
            float4 kt1 = K2b[d * 256 +  64 + lane];
            float4 kt2 = K2b[d * 256 + 128 + lane];
            float4 kt3 = K2b[d * 256 + 192 + lane];
            #pragma unroll
            for (int r = 0; r < QR; ++r) {
                const float qd = (dd == 0) ? qv[r].x : (dd == 1) ? qv[r].y
                               : (dd == 2) ? qv[r].z : qv[r].w;
                p[r][0].x += qd * kt0.x; p[r][0].y += qd * kt0.y;
                p[r][0].z += qd * kt0.z; p[r][0].w += qd * kt0.w;
                p[r][1].x += qd * kt1.x; p[r][1].y += qd * kt1.y;
                p[r][1].z += qd * kt1.z; p[r][1].w += qd * kt1.w;
                p[r][2].x += qd * kt2.x; p[r][2].y += qd * kt2.y;
                p[r][2].z += qd * kt2.z; p[r][2].w += qd * kt2.w;
                p[r][3].x += qd * kt3.x; p[r][3].y += qd * kt3.y;
                p[r][3].z += qd * kt3.z; p[r][3].w += qd * kt3.w;
            }
        }
    }

    #pragma unroll
    for (int r = 0; r < QR; ++r) {
        float sum = 0.f;
        #pragma unroll
        for (int j = 0; j < 4; ++j) {
            p[r][j].x = __expf(p[r][j].x);
            p[r][j].y = __expf(p[r][j].y);
            p[r][j].z = __expf(p[r][j].z);
            p[r][j].w = __expf(p[r][j].w);
            sum += p[r][j].x + p[r][j].y + p[r][j].z + p[r][j].w;
        }
        #pragma unroll
        for (int off = 1; off < 64; off <<= 1) sum += __shfl_xor(sum, off);
        const float iv = 1.f / sum;
        float4* orow = (float4*)(out2 + ((size_t)row0 + wid * QR + r) * SS);
        #pragma unroll
        for (int j = 0; j < 4; ++j)
            orow[j * 64 + lane] = make_float4(p[r][j].x * iv, p[r][j].y * iv,
                                              p[r][j].z * iv, p[r][j].w * iv);
    }
}

// ---------------------------------------------------------------------------
extern "C" void kernel_launch(void* const* d_in, const int* in_sizes, int n_in,
                              void* d_out, int out_size, void* d_ws, size_t ws_size,
                              hipStream_t stream) {
    const float* inp = (const float*)d_in[0];
    const float* Wq  = (const float*)d_in[1];
    const float* bq  = (const float*)d_in[2];
    const float* Wk  = (const float*)d_in[3];
    const float* bk  = (const float*)d_in[4];
    const float* Wv  = (const float*)d_in[5];
    const float* bv  = (const float*)d_in[6];
    const float* lnw = (const float*)d_in[7];
    const float* lnb = (const float*)d_in[8];
    const float* W1  = (const float*)d_in[9];
    const float* b1  = (const float*)d_in[10];
    const float* Wq2 = (const float*)d_in[11];
    const float* bq2 = (const float*)d_in[12];
    const float* Wk2 = (const float*)d_in[13];
    const float* bk2 = (const float*)d_in[14];

    float* out0 = (float*)d_out;                 // [16,1024,7]
    float* out2 = out0 + ROWS * NIN;             // [16,1024,1024]

    float* ws = (float*)d_ws;
    float* Qo  = ws;
    float* Ko  = ws + (size_t)QKV_ELEMS;
    float* Vo  = ws + (size_t)2 * QKV_ELEMS;
    float* A   = ws + (size_t)3 * QKV_ELEMS;
    float* Q2  = ws + (size_t)4 * QKV_ELEMS;
    float* K2T = ws + (size_t)5 * QKV_ELEMS;     // [B,28,S]

    k_proj <<<ROWS / 256, 256, 0, stream>>>(inp, Wq, bq, Wk, bk, Wv, bv, Qo, Ko, Vo);
    k_attn1<<<BB * NH * 8, 256, 0, stream>>>(Qo, Ko, Vo, A);
    k_lnffn<<<ROWS / 256, 256, 0, stream>>>(A, inp, lnw, lnb, W1, b1,
                                            Wq2, bq2, Wk2, bk2, out0, Q2, K2T);
    k_attn2<<<ROWS / 16, 256, 0, stream>>>(Q2, K2T, out2);
}

// Round 4
// 216.467 us; speedup vs baseline: 2.2870x; 2.2870x over previous
//
#include <hip/hip_runtime.h>

// Problem constants (fixed by reference)
#define BB 16
#define SS 1024
#define NIN 7
#define NHID 28
#define NH 7
#define DH 4

constexpr int ROWS = BB * SS;                 // 16384
constexpr int QKV_ELEMS = BB * NH * SS * DH;  // 458752 floats per tensor

// ---------------------------------------------------------------------------
// Kernel 1: QKV projection. inputs [B,S,7] @ W[7,28] + b -> Q,K,V in
// head-major layout [B][H][S][4]. Q pre-scaled by 1/sqrt(DH)=0.5.
// ---------------------------------------------------------------------------
__global__ __launch_bounds__(256) void k_proj(
    const float* __restrict__ inp,
    const float* __restrict__ Wq, const float* __restrict__ bq,
    const float* __restrict__ Wk, const float* __restrict__ bk,
    const float* __restrict__ Wv, const float* __restrict__ bv,
    float* __restrict__ Qo, float* __restrict__ Ko, float* __restrict__ Vo)
{
    __shared__ float  xs[256 * NIN];   // 7 KB: 256 rows of inputs
    __shared__ float4 w4[147];         // Wq(49) | Wk(49) | Wv(49) as float4
    __shared__ float4 b4[21];          // bq(7) | bk(7) | bv(7)

    const int tid  = threadIdx.x;
    const int row0 = blockIdx.x * 256;

    #pragma unroll
    for (int i = 0; i < NIN; ++i) xs[tid + 256 * i] = inp[row0 * NIN + tid + 256 * i];

    if (tid < 147) {
        const float* src = (tid < 49) ? Wq : (tid < 98) ? Wk : Wv;
        int off = (tid < 49) ? tid : (tid < 98) ? tid - 49 : tid - 98;
        w4[tid] = ((const float4*)src)[off];
    } else if (tid < 168) {
        int t = tid - 147;
        const float* src = (t < 7) ? bq : (t < 14) ? bk : bv;
        b4[t] = ((const float4*)src)[t % 7];
    }
    __syncthreads();

    const int r = row0 + tid;
    const int b = r >> 10, s = r & 1023;

    float x[NIN];
    #pragma unroll
    for (int i = 0; i < NIN; ++i) x[i] = xs[tid * NIN + i];

    float4 q[NH], k[NH], v[NH];
    #pragma unroll
    for (int j4 = 0; j4 < NH; ++j4) { q[j4] = b4[j4]; k[j4] = b4[7 + j4]; v[j4] = b4[14 + j4]; }

    #pragma unroll
    for (int i = 0; i < NIN; ++i) {
        const float xi = x[i];
        #pragma unroll
        for (int j4 = 0; j4 < NH; ++j4) {
            float4 wq = w4[i * 7 + j4];
            float4 wk = w4[49 + i * 7 + j4];
            float4 wv = w4[98 + i * 7 + j4];
            q[j4].x += xi * wq.x; q[j4].y += xi * wq.y; q[j4].z += xi * wq.z; q[j4].w += xi * wq.w;
            k[j4].x += xi * wk.x; k[j4].y += xi * wk.y; k[j4].z += xi * wk.z; k[j4].w += xi * wk.w;
            v[j4].x += xi * wv.x; v[j4].y += xi * wv.y; v[j4].z += xi * wv.z; v[j4].w += xi * wv.w;
        }
    }

    #pragma unroll
    for (int j4 = 0; j4 < NH; ++j4) {
        const int idx = (b * NH + j4) * SS + s;   // float4 index
        float4 qs = make_float4(0.5f * q[j4].x, 0.5f * q[j4].y, 0.5f * q[j4].z, 0.5f * q[j4].w);
        ((float4*)Qo)[idx] = qs;
        ((float4*)Ko)[idx] = k[j4];
        ((float4*)Vo)[idx] = v[j4];
    }
}

// ---------------------------------------------------------------------------
// Kernel 2: attention 1. Block = (b,h,qtile 256), 256 threads.
// Thread (ql=tid&63, kq=tid>>6) owns FOUR queries {qt*256 + r*64 + ql} over
// keys [kq*256, kq*256+256). kq is wave-uniform -> K/V LDS reads are
// broadcasts, and each read is reused by 4 queries (4x fewer LDS reads
// than 1-query-per-thread; attn1 was LDS-pipe-bound). kq-partials merged
// through LDS once. 448 blocks.
// ---------------------------------------------------------------------------
__global__ __launch_bounds__(256) void k_attn1(
    const float* __restrict__ Qo, const float* __restrict__ Ko,
    const float* __restrict__ Vo, float* __restrict__ A)
{
    __shared__ float4 Ksh[SS];        // 16 KB
    __shared__ float4 Vsh[SS];        // 16 KB
    __shared__ float4 pacc[4][256];   // 16 KB partial acc per kq
    __shared__ float  pl[4][256];     // 4 KB partial l per kq

    const int bh  = blockIdx.x >> 2;
    const int qt  = blockIdx.x & 3;
    const int tid = threadIdx.x;

    const float4* Kg = (const float4*)Ko + (size_t)bh * SS;
    const float4* Vg = (const float4*)Vo + (size_t)bh * SS;
    #pragma unroll
    for (int i = 0; i < 4; ++i) {
        Ksh[tid + 256 * i] = Kg[tid + 256 * i];
        Vsh[tid + 256 * i] = Vg[tid + 256 * i];
    }
    __syncthreads();

    const int ql = tid & 63;
    const int kq = tid >> 6;          // wave id (uniform within wave)

    float4 qv[4];
    #pragma unroll
    for (int r = 0; r < 4; ++r)
        qv[r] = ((const float4*)Qo)[(size_t)bh * SS + qt * 256 + r * 64 + ql];

    float4 acc[4];
    float  l[4];
    #pragma unroll
    for (int r = 0; r < 4; ++r) { acc[r] = make_float4(0.f, 0.f, 0.f, 0.f); l[r] = 0.f; }

    const int k0 = kq << 8;
    #pragma unroll 2
    for (int kk = k0; kk < k0 + 256; ++kk) {
        float4 kr = Ksh[kk];          // wave-uniform broadcast
        float4 vr = Vsh[kk];
        #pragma unroll
        for (int r = 0; r < 4; ++r) {
            float s = qv[r].x * kr.x + qv[r].y * kr.y + qv[r].z * kr.z + qv[r].w * kr.w;
            float p = __expf(s);
            l[r] += p;
            acc[r].x += p * vr.x; acc[r].y += p * vr.y;
            acc[r].z += p * vr.z; acc[r].w += p * vr.w;
        }
    }

    #pragma unroll
    for (int r = 0; r < 4; ++r) {
        pacc[kq][r * 64 + ql] = acc[r];
        pl[kq][r * 64 + ql]   = l[r];
    }
    __syncthreads();

    // merge the 4 k-quarters: thread tid owns query qt*256 + tid
    float4 a  = pacc[0][tid];
    float  ll = pl[0][tid];
    #pragma unroll
    for (int j = 1; j < 4; ++j) {
        float4 t = pacc[j][tid];
        a.x += t.x; a.y += t.y; a.z += t.z; a.w += t.w;
        ll += pl[j][tid];
    }
    const float inv = 1.f / ll;
    const int b = bh / NH, h = bh % NH;
    const int q = qt * 256 + tid;
    ((float4*)A)[(size_t)(b * SS + q) * NH + h] =
        make_float4(a.x * inv, a.y * inv, a.z * inv, a.w * inv);
}

// ---------------------------------------------------------------------------
// Kernel 3: LayerNorm(28) + FFN(28->7)+ReLU+residual -> out (output 0),
// then Q2 (row-major, pre-scaled 1/sqrt(7)) and K2 TRANSPOSED: K2T[b][d][s].
// ---------------------------------------------------------------------------
__global__ __launch_bounds__(256) void k_lnffn(
    const float* __restrict__ A, const float* __restrict__ inp,
    const float* __restrict__ lnw, const float* __restrict__ lnb,
    const float* __restrict__ W1, const float* __restrict__ b1,
    const float* __restrict__ Wq2, const float* __restrict__ bq2,
    const float* __restrict__ Wk2, const float* __restrict__ bk2,
    float* __restrict__ outp, float* __restrict__ Q2, float* __restrict__ K2T)
{
    const int r = blockIdx.x * 256 + threadIdx.x;

    float y[NHID];
    const float4* Ar = (const float4*)A + (size_t)r * 7;
    float mu = 0.f;
    #pragma unroll
    for (int j4 = 0; j4 < 7; ++j4) {
        float4 t = Ar[j4];
        y[4 * j4 + 0] = t.x; y[4 * j4 + 1] = t.y; y[4 * j4 + 2] = t.z; y[4 * j4 + 3] = t.w;
        mu += t.x + t.y + t.z + t.w;
    }
    mu *= (1.f / NHID);
    float var = 0.f;
    #pragma unroll
    for (int j = 0; j < NHID; ++j) { float d = y[j] - mu; var += d * d; }
    var *= (1.f / NHID);
    const float rstd = rsqrtf(var + 1e-5f);
    #pragma unroll
    for (int j = 0; j < NHID; ++j) y[j] = (y[j] - mu) * rstd * lnw[j] + lnb[j];

    float o[NIN];
    #pragma unroll
    for (int i = 0; i < NIN; ++i) {
        float a = b1[i];
        #pragma unroll
        for (int j = 0; j < NHID; ++j) a += y[j] * W1[j * NIN + i];
        o[i] = fmaxf(a, 0.f) + inp[r * NIN + i];
        outp[r * NIN + i] = o[i];
    }

    const float rs7 = 0.3779644730092272f;  // 1/sqrt(7)
    const int b = r >> 10, s = r & 1023;
    float* K2Tb = K2T + ((size_t)b * NHID) * SS + s;
    float4* Q2r = (float4*)Q2 + (size_t)r * 7;
    #pragma unroll
    for (int j4 = 0; j4 < 7; ++j4) {
        float qq[4];
        #pragma unroll
        for (int c = 0; c < 4; ++c) {
            int j = 4 * j4 + c;
            float aq = bq2[j], ak = bk2[j];
            #pragma unroll
            for (int i = 0; i < NIN; ++i) {
                aq += o[i] * Wq2[i * NHID + j];
                ak += o[i] * Wk2[i * NHID + j];
            }
            qq[c] = aq * rs7;
            K2Tb[(size_t)j * SS] = ak;      // coalesced per-j
        }
        Q2r[j4] = make_float4(qq[0], qq[1], qq[2], qq[3]);
    }
}

// ---------------------------------------------------------------------------
// Kernel 4: attention 2 weights. Wave-autonomous: each wave owns 4 complete
// query rows (block = 4 waves = 16 rows; grid = 1024 blocks). Lane holds
// key-f4-chunks {lane+64j, j=0..3}: p[4][4] float4 = 64 VGPRs. Row sum via
// 64-lane shfl_xor butterfly; stores issue as soon as the wave is done.
// NOTE: no min-waves launch bound — R3's (256,4) clamped VGPRs to 64 and
// spilled p to scratch (1 GB of HBM spill traffic, 4.4x regression).
// ---------------------------------------------------------------------------
#define QR 4
__global__ __launch_bounds__(256) void k_attn2(
    const float* __restrict__ Q2, const float* __restrict__ K2T,
    float* __restrict__ out2)
{
    __shared__ float q2s[16 * NHID];   // 448 floats

    const int tid  = threadIdx.x;
    const int lane = tid & 63;
    const int wid  = tid >> 6;
    const int row0 = blockIdx.x * 16;          // global row = b*1024 + s
    const int b    = row0 >> 10;

    if (tid < 112) ((float4*)q2s)[tid] = ((const float4*)Q2)[(size_t)row0 * 7 + tid];
    __syncthreads();

    const float*  qw  = q2s + wid * QR * NHID;              // this wave's 4 rows
    const float4* K2b = (const float4*)(K2T + (size_t)b * NHID * SS);  // [28][256] f4

    float4 p[QR][4];
    #pragma unroll
    for (int r = 0; r < QR; ++r)
        #pragma unroll
        for (int j = 0; j < 4; ++j) p[r][j] = make_float4(0.f, 0.f, 0.f, 0.f);

    #pragma unroll
    for (int d4 = 0; d4 < 7; ++d4) {
        float4 qv[QR];
        #pragma unroll
        for (int r = 0; r < QR; ++r) qv[r] = ((const float4*)qw)[r * 7 + d4];  // broadcast
        #pragma unroll
        for (int dd = 0; dd < 4; ++dd) {
            const int d = d4 * 4 + dd;
            float4 kt0 = K2b[d * 256 +       lane];
            float4 kt1 = K2b[d * 256 +  64 + lane];
            float4 kt2 = K2b[d * 256 + 128 + lane];
            float4 kt3 = K2b[d * 256 + 192 + lane];
            #pragma unroll
            for (int r = 0; r < QR; ++r) {
                const float qd = (dd == 0) ? qv[r].x : (dd == 1) ? qv[r].y
                               : (dd == 2) ? qv[r].z : qv[r].w;
                p[r][0].x += qd * kt0.x; p[r][0].y += qd * kt0.y;
                p[r][0].z += qd * kt0.z; p[r][0].w += qd * kt0.w;
                p[r][1].x += qd * kt1.x; p[r][1].y += qd * kt1.y;
                p[r][1].z += qd * kt1.z; p[r][1].w += qd * kt1.w;
                p[r][2].x += qd * kt2.x; p[r][2].y += qd * kt2.y;
                p[r][2].z += qd * kt2.z; p[r][2].w += qd * kt2.w;
                p[r][3].x += qd * kt3.x; p[r][3].y += qd * kt3.y;
                p[r][3].z += qd * kt3.z; p[r][3].w += qd * kt3.w;
            }
        }
    }

    #pragma unroll
    for (int r = 0; r < QR; ++r) {
        float sum = 0.f;
        #pragma unroll
        for (int j = 0; j < 4; ++j) {
            p[r][j].x = __expf(p[r][j].x);
            p[r][j].y = __expf(p[r][j].y);
            p[r][j].z = __expf(p[r][j].z);
            p[r][j].w = __expf(p[r][j].w);
            sum += p[r][j].x + p[r][j].y + p[r][j].z + p[r][j].w;
        }
        #pragma unroll
        for (int off = 1; off < 64; off <<= 1) sum += __shfl_xor(sum, off);
        const float iv = 1.f / sum;
        float4* orow = (float4*)(out2 + ((size_t)row0 + wid * QR + r) * SS);
        #pragma unroll
        for (int j = 0; j < 4; ++j)
            orow[j * 64 + lane] = make_float4(p[r][j].x * iv, p[r][j].y * iv,
                                              p[r][j].z * iv, p[r][j].w * iv);
    }
}

// ---------------------------------------------------------------------------
extern "C" void kernel_launch(void* const* d_in, const int* in_sizes, int n_in,
                              void* d_out, int out_size, void* d_ws, size_t ws_size,
                              hipStream_t stream) {
    const float* inp = (const float*)d_in[0];
    const float* Wq  = (const float*)d_in[1];
    const float* bq  = (const float*)d_in[2];
    const float* Wk  = (const float*)d_in[3];
    const float* bk  = (const float*)d_in[4];
    const float* Wv  = (const float*)d_in[5];
    const float* bv  = (const float*)d_in[6];
    const float* lnw = (const float*)d_in[7];
    const float* lnb = (const float*)d_in[8];
    const float* W1  = (const float*)d_in[9];
    const float* b1  = (const float*)d_in[10];
    const float* Wq2 = (const float*)d_in[11];
    const float* bq2 = (const float*)d_in[12];
    const float* Wk2 = (const float*)d_in[13];
    const float* bk2 = (const float*)d_in[14];

    float* out0 = (float*)d_out;                 // [16,1024,7]
    float* out2 = out0 + ROWS * NIN;             // [16,1024,1024]

    float* ws = (float*)d_ws;
    float* Qo  = ws;
    float* Ko  = ws + (size_t)QKV_ELEMS;
    float* Vo  = ws + (size_t)2 * QKV_ELEMS;
    float* A   = ws + (size_t)3 * QKV_ELEMS;
    float* Q2  = ws + (size_t)4 * QKV_ELEMS;
    float* K2T = ws + (size_t)5 * QKV_ELEMS;     // [B,28,S]

    k_proj <<<ROWS / 256, 256, 0, stream>>>(inp, Wq, bq, Wk, bk, Wv, bv, Qo, Ko, Vo);
    k_attn1<<<BB * NH * 4, 256, 0, stream>>>(Qo, Ko, Vo, A);
    k_lnffn<<<ROWS / 256, 256, 0, stream>>>(A, inp, lnw, lnb, W1, b1,
                                            Wq2, bq2, Wk2, bk2, out0, Q2, K2T);
    k_attn2<<<ROWS / 16, 256, 0, stream>>>(Q2, K2T, out2);
}